// Round 8
// baseline (276.296 us; speedup 1.0000x reference)
//
#include <hip/hip_runtime.h>

// MHA B=2, T=2048, D=1024, H=16, nd=64. fp32 I/O, bf16 MFMA internally.
// softmax over QUERY axis (dim=-2), causal, fixed-max (|z|<~3):
//   l[tk] = sum_{tq>=tk} exp(z); out[tq] = sum_{tk<=tq} exp(z)/l[tk] * v[tk]
// log2(e)/8 folded into Q projection so softmax uses raw v_exp_f32 (exp2).
// q,k,v pre-converted to bf16 so ALL GEMM K-loops are pure dual
// global_load_lds (m97 structure, 32 MFMA/wave/K-step) — round-6 counters
// showed the fp32-A register path capped MfmaUtil at 14%.
// All LDS tiles XOR-swizzled (slot g of row r holds granule g^(r&7)): round-6
// measured 0 bank conflicts with this scheme.

#define Dd 1024
#define Tt 2048
#define Bb 2
#define Hh 16
#define NDh 64
#define Mm (Bb * Tt)

using u16 = unsigned short;
using u32 = unsigned int;
typedef __attribute__((ext_vector_type(8))) short bf16x8;
typedef __attribute__((ext_vector_type(4))) float f32x4;

__device__ __forceinline__ u16 f2bf(float f) {
  return (u16)((__float_as_uint(f) + 0x8000u) >> 16);
}
__device__ __forceinline__ float fexp2(float x) {
  return __builtin_amdgcn_exp2f(x);  // v_exp_f32 (NOT __exp2f: glibc collision)
}
// async global->LDS, 16B per lane; LDS dest = base + lane*16 (wave-uniform base)
__device__ __forceinline__ void ldsdma16(const u16* g, u16* l) {
  __builtin_amdgcn_global_load_lds(
      (const __attribute__((address_space(1))) u32*)g,
      (__attribute__((address_space(3))) u32*)l, 16, 0, 0);
}
#define MFMA(a, b, c) __builtin_amdgcn_mfma_f32_16x16x32_bf16((a), (b), (c), 0, 0, 0)
// frag load from swizzled 64-elem-row tile
__device__ __forceinline__ bf16x8 ldfrag(const u16* lds, int row, int kgrp) {
  return *(const bf16x8*)(lds + row * 64 + (((kgrp) ^ (row & 7)) * 8));
}

// ---------------------------------------------------------------------------
// Convert 4 weights + q,k,v (fp32 -> bf16); zero d_out and lsum.
// vid < 1M: weights; else inputs. Grid 16384 x 256 = 4M vec4 slots.
// ---------------------------------------------------------------------------
__global__ __launch_bounds__(256) void cvt_all(
    const float* __restrict__ w0, const float* __restrict__ w1,
    const float* __restrict__ w2, const float* __restrict__ w3,
    const float* __restrict__ q, const float* __restrict__ k,
    const float* __restrict__ v,
    u16* __restrict__ Wb, u16* __restrict__ Xb,
    float* __restrict__ outz, float* __restrict__ lsumz)
{
  const int vid = blockIdx.x * 256 + threadIdx.x;
  const float* s;
  u16* d;
  if (vid < (1 << 20)) {
    const int seg = vid >> 18, off = (vid & 0x3FFFF) * 4;
    s = (seg == 0 ? w0 : seg == 1 ? w1 : seg == 2 ? w2 : w3) + off;
    d = Wb + (size_t)seg * Dd * Dd + off;
    *(float4*)(outz + (size_t)vid * 4) = make_float4(0.f, 0.f, 0.f, 0.f);
    if (vid < Bb * Hh * Tt / 4)
      *(float4*)(lsumz + (size_t)vid * 4) = make_float4(0.f, 0.f, 0.f, 0.f);
  } else {
    const int iv = vid - (1 << 20);
    const int seg = iv >> 20, off = (iv & 0xFFFFF) * 4;
    s = (seg == 0 ? q : seg == 1 ? k : v) + off;
    d = Xb + (size_t)seg * Mm * Dd + off;
  }
  float4 f = *(const float4*)s;
  ushort4 o;
  o.x = f2bf(f.x); o.y = f2bf(f.y); o.z = f2bf(f.z); o.w = f2bf(f.w);
  *(ushort4*)d = o;
}

// ---------------------------------------------------------------------------
// All-bf16 GEMM body (m97 structure): Y[m,n] = sum_k X[m,k]*W[n,k] + bias[n].
// BM=128, BN=128, BK=64; 256 thr / 4 waves; wave tile 64x64 = 4x4 frags;
// 32 MFMA + 16 ds_read_b128 per wave per K-step; A and B both via DMA.
// omode 0: bf16 Y[m*Dd+n] * oscale;  1: bf16 transposed (Y[b,n,t]);
//       2: f32 atomicAdd (split-K; bias on kc==0).
// ---------------------------------------------------------------------------
__device__ __forceinline__ void gemm_body(
    const u16* __restrict__ X, const u16* __restrict__ WB,
    const float* __restrict__ bias, void* Yv, float oscale,
    int omode, int kc, int knum, u16* As, u16* Bs)
{
  const int t = threadIdx.x, lane = t & 63, w = t >> 6;
  const int col = lane & 15, quad = lane >> 4;
  const int m0 = blockIdx.x * 128, n0 = blockIdx.y * 128;
  const int wm = (w >> 1) * 64, wn = (w & 1) * 64;
  const int drr = lane >> 3, dsw = ((lane & 7) ^ drr) * 8;  // swizzled src col
  const int kbeg = (Dd / knum) * kc, kend = kbeg + Dd / knum;

  f32x4 acc[4][4] = {};

  for (int k0 = kbeg; k0 < kend; k0 += 64) {
    __syncthreads();  // previous iteration's frag readers done
#pragma unroll
    for (int i = 0; i < 4; i++) {
      const int rr = w * 32 + i * 8;
      ldsdma16(X + (size_t)(m0 + rr + drr) * Dd + k0 + dsw, As + rr * 64);
      ldsdma16(WB + (size_t)(n0 + rr + drr) * Dd + k0 + dsw, Bs + rr * 64);
    }
    __syncthreads();  // drains dma (vmcnt)
#pragma unroll
    for (int s = 0; s < 2; s++) {
      bf16x8 a[4], b[4];
#pragma unroll
      for (int i = 0; i < 4; i++)
        a[i] = ldfrag(As, wm + i * 16 + col, s * 4 + quad);
#pragma unroll
      for (int j = 0; j < 4; j++)
        b[j] = ldfrag(Bs, wn + j * 16 + col, s * 4 + quad);
#pragma unroll
      for (int i = 0; i < 4; i++)
#pragma unroll
        for (int j = 0; j < 4; j++)
          acc[i][j] = MFMA(a[i], b[j], acc[i][j]);
    }
  }

#pragma unroll
  for (int jt = 0; jt < 4; jt++) {
    const int n = n0 + wn + jt * 16 + col;
    const float bn = (omode == 2 && kc != 0) ? 0.f : bias[n];
    if (omode == 1) {
#pragma unroll
      for (int i = 0; i < 4; i++) {
        const int mg = m0 + wm + i * 16 + quad * 4;
        const int bb = mg >> 11, tl = mg & 2047;
        ushort4 o;
        o.x = f2bf(acc[i][jt][0] + bn);
        o.y = f2bf(acc[i][jt][1] + bn);
        o.z = f2bf(acc[i][jt][2] + bn);
        o.w = f2bf(acc[i][jt][3] + bn);
        *(ushort4*)((u16*)Yv + (size_t)bb * Dd * Tt + (size_t)n * Tt + tl) = o;
      }
    } else if (omode == 0) {
      u16* Y = (u16*)Yv;
#pragma unroll
      for (int i = 0; i < 4; i++)
#pragma unroll
        for (int r = 0; r < 4; r++) {
          const int m = m0 + wm + i * 16 + quad * 4 + r;
          Y[(size_t)m * Dd + n] = f2bf((acc[i][jt][r] + bn) * oscale);
        }
    } else {
      float* Y = (float*)Yv;
#pragma unroll
      for (int i = 0; i < 4; i++)
#pragma unroll
        for (int r = 0; r < 4; r++) {
          const int m = m0 + wm + i * 16 + quad * 4 + r;
          atomicAdd(&Y[(size_t)m * Dd + n], acc[i][jt][r] + bn);
        }
    }
  }
}

// Fused Q/K/V projection: blockIdx.z selects input/weight/output.
// Q is scaled by log2(e)/8 so attention uses exp2 directly.
__global__ __launch_bounds__(256) void proj_qkv(
    const u16* __restrict__ Xb, const u16* __restrict__ Wb,
    const float* __restrict__ bq, const float* __restrict__ bk,
    const float* __restrict__ bv,
    u16* __restrict__ Qp, u16* __restrict__ Kp, u16* __restrict__ VtG)
{
  __shared__ u16 As[128 * 64];
  __shared__ u16 Bs[128 * 64];
  const int z = blockIdx.z;
  const u16* X = Xb + (size_t)z * Mm * Dd;
  const u16* W = Wb + (size_t)z * Dd * Dd;
  const float* bias = z == 0 ? bq : z == 1 ? bk : bv;
  void* Y = z == 0 ? (void*)Qp : z == 1 ? (void*)Kp : (void*)VtG;
  const float qs = 0.125f * 1.44269504088896f;  // 1/sqrt(nd) * log2(e)
  gemm_body(X, W, bias, Y, z == 0 ? qs : 1.0f, z == 2 ? 1 : 0, 0, 1, As, Bs);
}

__global__ __launch_bounds__(256) void gemm_final(
    const u16* __restrict__ Ctx, const u16* __restrict__ Wcb,
    const float* __restrict__ bc, float* __restrict__ out)
{
  __shared__ u16 As[128 * 64];
  __shared__ u16 Bs[128 * 64];
  gemm_body(Ctx, Wcb, bc, out, 1.0f, 2, blockIdx.z, 2, As, Bs);
}

// ---------------------------------------------------------------------------
// Pass A: lsum[tk] += partial sum_{tq>=tk} exp2(z).  Block: (bh, 128 tk,
// chunk c of tq-tiles). Wave: 32 tk (2 A-strips held in regs). Q-tiles of 128.
// ---------------------------------------------------------------------------
__global__ __launch_bounds__(256) void attn_stats(
    const u16* __restrict__ Qp, const u16* __restrict__ Kp,
    float* __restrict__ lsum)
{
  __shared__ u16 Ks[128 * 64];
  __shared__ u16 Qs[128 * 64];
  const int t = threadIdx.x, lane = t & 63, w = t >> 6;
  const int col = lane & 15, quad = lane >> 4;
  const int bh = blockIdx.x, b = bh >> 4, h = bh & 15;
  const int j = blockIdx.y, tk0 = j * 128, c = blockIdx.z;
  const u16* Kbase = Kp + (size_t)b * Tt * Dd + h * NDh;
  const u16* Qbase = Qp + (size_t)b * Tt * Dd + h * NDh;
  const int drr = lane >> 3, dsw = ((lane & 7) ^ drr) * 8;

#pragma unroll
  for (int i = 0; i < 4; i++) {
    const int rr = w * 32 + i * 8;
    ldsdma16(Kbase + (size_t)(tk0 + rr + drr) * Dd + dsw, Ks + rr * 64);
  }
  __syncthreads();
  bf16x8 ka[2][2];
#pragma unroll
  for (int s2 = 0; s2 < 2; s2++) {
    const int row = w * 32 + s2 * 16 + col;
    ka[s2][0] = ldfrag(Ks, row, quad);
    ka[s2][1] = ldfrag(Ks, row, 4 + quad);
  }

  float l[2][4] = {};

  for (int jj = j + c; jj < Tt / 128; jj += 2) {
    const bool masked = (jj == j);
    const int tq0 = jj * 128;
    __syncthreads();  // prev Qs readers done
#pragma unroll
    for (int i = 0; i < 4; i++) {
      const int rr = w * 32 + i * 8;
      ldsdma16(Qbase + (size_t)(tq0 + rr + drr) * Dd + dsw, Qs + rr * 64);
    }
    __syncthreads();
#pragma unroll
    for (int jt = 0; jt < 8; jt++) {
      bf16x8 qb0 = ldfrag(Qs, jt * 16 + col, quad);
      bf16x8 qb1 = ldfrag(Qs, jt * 16 + col, 4 + quad);
      const int tq = tq0 + jt * 16 + col;
#pragma unroll
      for (int s2 = 0; s2 < 2; s2++) {
        f32x4 z = {};
        z = MFMA(ka[s2][0], qb0, z);
        z = MFMA(ka[s2][1], qb1, z);
#pragma unroll
        for (int r = 0; r < 4; r++) {
          float e = fexp2(z[r]);
          if (masked) {
            const int tk = tk0 + w * 32 + s2 * 16 + quad * 4 + r;
            e = (tq >= tk) ? e : 0.f;
          }
          l[s2][r] += e;
        }
      }
    }
  }

#pragma unroll
  for (int s2 = 0; s2 < 2; s2++)
#pragma unroll
    for (int r = 0; r < 4; r++) {
      float s = l[s2][r];
#pragma unroll
      for (int m = 1; m < 16; m <<= 1) s += __shfl_xor(s, m);
      if (col == 0)
        atomicAdd(&lsum[(size_t)bh * Tt + tk0 + w * 32 + s2 * 16 + quad * 4 + r], s);
    }
}

// ---------------------------------------------------------------------------
// Pass B: out[tq] = sum_{tk<=tq} exp2(z)/l[tk] * v[tk].  Block: (bh, 128 tq),
// wave: 32 tq (2 A-strips). tk-tiles of 64. V pre-transposed VtG[b,h*64+d,t].
// Q LDS reused as P (wave-private rows). Heavy blocks first (reversed y).
// ---------------------------------------------------------------------------
__global__ __launch_bounds__(256) void attn_out(
    const u16* __restrict__ Qp, const u16* __restrict__ Kp,
    const u16* __restrict__ VtG, const float* __restrict__ lsum,
    u16* __restrict__ Ctx)
{
  __shared__ u16 QPs[128 * 64];  // Q at start, then P (wave-private rows)
  __shared__ u16 Ks[64 * 64];
  __shared__ u16 Vts[64 * 64];   // [d][tk]
  __shared__ float srl[64];
  const int t = threadIdx.x, lane = t & 63, w = t >> 6;
  const int col = lane & 15, quad = lane >> 4;
  const int bh = blockIdx.x, b = bh >> 4, h = bh & 15;
  const int tq0 = (gridDim.y - 1 - blockIdx.y) * 128;   // heavy-first
  const u16* Qbase = Qp + (size_t)b * Tt * Dd + h * NDh;
  const u16* Kbase = Kp + (size_t)b * Tt * Dd + h * NDh;
  const u16* Vbase = VtG + (size_t)b * Dd * Tt + (size_t)h * NDh * Tt;
  const int drr = lane >> 3, dsw = ((lane & 7) ^ drr) * 8;

#pragma unroll
  for (int i = 0; i < 4; i++) {
    const int rr = w * 32 + i * 8;
    ldsdma16(Qbase + (size_t)(tq0 + rr + drr) * Dd + dsw, QPs + rr * 64);
  }
  __syncthreads();
  bf16x8 qa[2][2];
#pragma unroll
  for (int s2 = 0; s2 < 2; s2++) {
    const int row = w * 32 + s2 * 16 + col;
    qa[s2][0] = ldfrag(QPs, row, quad);
    qa[s2][1] = ldfrag(QPs, row, 4 + quad);
  }

  f32x4 o[2][4] = {};

  for (int tk0 = 0; tk0 < tq0 + 128; tk0 += 64) {
    const bool masked = (tk0 >= tq0);
    __syncthreads();  // prev iter LDS readers done
#pragma unroll
    for (int i = 0; i < 2; i++) {
      const int rr = w * 16 + i * 8;
      ldsdma16(Kbase + (size_t)(tk0 + rr + drr) * Dd + dsw, Ks + rr * 64);
      ldsdma16(Vbase + (size_t)(rr + drr) * Tt + tk0 + dsw, Vts + rr * 64);
    }
    if (t < 64) srl[t] = 1.0f / lsum[(size_t)bh * Tt + tk0 + t];
    __syncthreads();
#pragma unroll
    for (int jt = 0; jt < 4; jt++) {
      bf16x8 kb0 = ldfrag(Ks, jt * 16 + col, quad);
      bf16x8 kb1 = ldfrag(Ks, jt * 16 + col, 4 + quad);
      const int tkl = jt * 16 + col;
      const float rl = srl[tkl];
#pragma unroll
      for (int s2 = 0; s2 < 2; s2++) {
        f32x4 z = {};
        z = MFMA(qa[s2][0], kb0, z);
        z = MFMA(qa[s2][1], kb1, z);
#pragma unroll
        for (int r = 0; r < 4; r++) {
          const int row = w * 32 + s2 * 16 + quad * 4 + r;
          float p = fexp2(z[r]) * rl;
          if (masked) p = (tk0 + tkl <= tq0 + row) ? p : 0.f;
          QPs[row * 64 + (((tkl >> 3) ^ (row & 7)) * 8) + (tkl & 7)] = f2bf(p);
        }
      }
    }
    // no barrier: each wave reads only its own 32 P rows (same-wave LDS order)
    bf16x8 pa[2][2];
#pragma unroll
    for (int s2 = 0; s2 < 2; s2++) {
      const int row = w * 32 + s2 * 16 + col;
      pa[s2][0] = ldfrag(QPs, row, quad);
      pa[s2][1] = ldfrag(QPs, row, 4 + quad);
    }
#pragma unroll
    for (int dn = 0; dn < 4; dn++) {
      bf16x8 vb0 = ldfrag(Vts, dn * 16 + col, quad);
      bf16x8 vb1 = ldfrag(Vts, dn * 16 + col, 4 + quad);
#pragma unroll
      for (int s2 = 0; s2 < 2; s2++) {
        o[s2][dn] = MFMA(pa[s2][0], vb0, o[s2][dn]);
        o[s2][dn] = MFMA(pa[s2][1], vb1, o[s2][dn]);
      }
    }
  }

#pragma unroll
  for (int s2 = 0; s2 < 2; s2++)
#pragma unroll
    for (int dn = 0; dn < 4; dn++)
#pragma unroll
      for (int r = 0; r < 4; r++) {
        const int tq = tq0 + w * 32 + s2 * 16 + quad * 4 + r;
        Ctx[(size_t)(b * Tt + tq) * Dd + h * NDh + dn * 16 + col] = f2bf(o[s2][dn][r]);
      }
}

// ---------------------------------------------------------------------------
extern "C" void kernel_launch(void* const* d_in, const int* in_sizes, int n_in,
                              void* d_out, int out_size, void* d_ws, size_t ws_size,
                              hipStream_t stream)
{
  const float* q  = (const float*)d_in[0];
  const float* k  = (const float*)d_in[1];
  const float* v  = (const float*)d_in[2];
  const float* Wq = (const float*)d_in[3];
  const float* bq = (const float*)d_in[4];
  const float* Wk = (const float*)d_in[5];
  const float* bk = (const float*)d_in[6];
  const float* Wv = (const float*)d_in[7];
  const float* bv = (const float*)d_in[8];
  const float* Wc = (const float*)d_in[9];
  const float* bc = (const float*)d_in[10];

  u16* Wb   = (u16*)d_ws;                         // 4 * Dd*Dd
  u16* Xb   = Wb + (size_t)4 * Dd * Dd;           // 3 * Mm*Dd (q,k,v bf16)
  u16* Qp   = Xb + (size_t)3 * Mm * Dd;
  u16* Kp   = Qp + (size_t)Mm * Dd;
  u16* VtG  = Kp + (size_t)Mm * Dd;               // [B, D, T] transposed
  u16* Ctx  = VtG + (size_t)Mm * Dd;
  float* lsum = (float*)(Ctx + (size_t)Mm * Dd);  // Bb*Hh*Tt

  cvt_all<<<16384, 256, 0, stream>>>(Wq, Wk, Wv, Wc, q, k, v, Wb, Xb,
                                     (float*)d_out, lsum);
  proj_qkv<<<dim3(Mm / 128, Dd / 128, 3), 256, 0, stream>>>(
      Xb, Wb, bq, bk, bv, Qp, Kp, VtG);
  attn_stats<<<dim3(Bb * Hh, Tt / 128, 2), 256, 0, stream>>>(Qp, Kp, lsum);
  attn_out<<<dim3(Bb * Hh, Tt / 128), 256, 0, stream>>>(Qp, Kp, VtG, lsum, Ctx);
  gemm_final<<<dim3(Mm / 128, Dd / 128, 2), 256, 0, stream>>>(
      Ctx, Wb + (size_t)3 * Dd * Dd, bc, (float*)d_out);
}

// Round 9
// 270.483 us; speedup vs baseline: 1.0215x; 1.0215x over previous
//
#include <hip/hip_runtime.h>

// MHA B=2, T=2048, D=1024, H=16, nd=64. fp32 I/O, bf16 MFMA internally.
// softmax over QUERY axis (dim=-2), causal, fixed-max (|z|<~3):
//   l[tk] = sum_{tq>=tk} exp(z); out[tq] = sum_{tk<=tq} exp(z)/l[tk] * v[tk]
// log2(e)/8 folded into Q projection so softmax uses raw v_exp_f32 (exp2).
// Round-8 counters: attn_out = critical path (61us, occupancy 11.5%) because
// the longest block runs 32 serial K-iterations. Round 9: 2-way tk-split
// (interleaved parity) halves the serial chain; blocks atomicAdd f32 partial
// outputs into a ctx accumulator aliased on the dead Xb region.

#define Dd 1024
#define Tt 2048
#define Bb 2
#define Hh 16
#define NDh 64
#define Mm (Bb * Tt)

using u16 = unsigned short;
using u32 = unsigned int;
typedef __attribute__((ext_vector_type(8))) short bf16x8;
typedef __attribute__((ext_vector_type(4))) float f32x4;

__device__ __forceinline__ u16 f2bf(float f) {
  return (u16)((__float_as_uint(f) + 0x8000u) >> 16);
}
__device__ __forceinline__ float fexp2(float x) {
  return __builtin_amdgcn_exp2f(x);  // v_exp_f32 (NOT __exp2f: glibc collision)
}
// async global->LDS, 16B per lane; LDS dest = base + lane*16 (wave-uniform base)
__device__ __forceinline__ void ldsdma16(const u16* g, u16* l) {
  __builtin_amdgcn_global_load_lds(
      (const __attribute__((address_space(1))) u32*)g,
      (__attribute__((address_space(3))) u32*)l, 16, 0, 0);
}
#define MFMA(a, b, c) __builtin_amdgcn_mfma_f32_16x16x32_bf16((a), (b), (c), 0, 0, 0)
// frag load from swizzled 64-elem-row tile (slot g of row r holds granule g^(r&7))
__device__ __forceinline__ bf16x8 ldfrag(const u16* lds, int row, int kgrp) {
  return *(const bf16x8*)(lds + row * 64 + (((kgrp) ^ (row & 7)) * 8));
}

// ---------------------------------------------------------------------------
// Convert 4 weights + q,k,v (fp32 -> bf16); zero d_out and lsum.
// ---------------------------------------------------------------------------
__global__ __launch_bounds__(256) void cvt_all(
    const float* __restrict__ w0, const float* __restrict__ w1,
    const float* __restrict__ w2, const float* __restrict__ w3,
    const float* __restrict__ q, const float* __restrict__ k,
    const float* __restrict__ v,
    u16* __restrict__ Wb, u16* __restrict__ Xb,
    float* __restrict__ outz, float* __restrict__ lsumz)
{
  const int vid = blockIdx.x * 256 + threadIdx.x;
  const float* s;
  u16* d;
  if (vid < (1 << 20)) {
    const int seg = vid >> 18, off = (vid & 0x3FFFF) * 4;
    s = (seg == 0 ? w0 : seg == 1 ? w1 : seg == 2 ? w2 : w3) + off;
    d = Wb + (size_t)seg * Dd * Dd + off;
    *(float4*)(outz + (size_t)vid * 4) = make_float4(0.f, 0.f, 0.f, 0.f);
    if (vid < Bb * Hh * Tt / 4)
      *(float4*)(lsumz + (size_t)vid * 4) = make_float4(0.f, 0.f, 0.f, 0.f);
  } else {
    const int iv = vid - (1 << 20);
    const int seg = iv >> 20, off = (iv & 0xFFFFF) * 4;
    s = (seg == 0 ? q : seg == 1 ? k : v) + off;
    d = Xb + (size_t)seg * Mm * Dd + off;
  }
  float4 f = *(const float4*)s;
  ushort4 o;
  o.x = f2bf(f.x); o.y = f2bf(f.y); o.z = f2bf(f.z); o.w = f2bf(f.w);
  *(ushort4*)d = o;
}

// ---------------------------------------------------------------------------
// All-bf16 GEMM body (m97 structure): Y[m,n] = sum_k X[m,k]*W[n,k] + bias[n].
// BM=BN=128, BK=64; 4 waves; wave 64x64 = 4x4 frags; 32 MFMA/wave/K-step.
// omode 0: bf16 Y*oscale; 1: bf16 transposed (Y[b,n,t]); 2: f32 atomicAdd.
// ---------------------------------------------------------------------------
__device__ __forceinline__ void gemm_body(
    const u16* __restrict__ X, const u16* __restrict__ WB,
    const float* __restrict__ bias, void* Yv, float oscale,
    int omode, int kc, int knum, u16* As, u16* Bs)
{
  const int t = threadIdx.x, lane = t & 63, w = t >> 6;
  const int col = lane & 15, quad = lane >> 4;
  const int m0 = blockIdx.x * 128, n0 = blockIdx.y * 128;
  const int wm = (w >> 1) * 64, wn = (w & 1) * 64;
  const int drr = lane >> 3, dsw = ((lane & 7) ^ drr) * 8;  // swizzled src col
  const int kbeg = (Dd / knum) * kc, kend = kbeg + Dd / knum;

  f32x4 acc[4][4] = {};

  for (int k0 = kbeg; k0 < kend; k0 += 64) {
    __syncthreads();  // previous iteration's frag readers done
#pragma unroll
    for (int i = 0; i < 4; i++) {
      const int rr = w * 32 + i * 8;
      ldsdma16(X + (size_t)(m0 + rr + drr) * Dd + k0 + dsw, As + rr * 64);
      ldsdma16(WB + (size_t)(n0 + rr + drr) * Dd + k0 + dsw, Bs + rr * 64);
    }
    __syncthreads();  // drains dma (vmcnt)
#pragma unroll
    for (int s = 0; s < 2; s++) {
      bf16x8 a[4], b[4];
#pragma unroll
      for (int i = 0; i < 4; i++)
        a[i] = ldfrag(As, wm + i * 16 + col, s * 4 + quad);
#pragma unroll
      for (int j = 0; j < 4; j++)
        b[j] = ldfrag(Bs, wn + j * 16 + col, s * 4 + quad);
#pragma unroll
      for (int i = 0; i < 4; i++)
#pragma unroll
        for (int j = 0; j < 4; j++)
          acc[i][j] = MFMA(a[i], b[j], acc[i][j]);
    }
  }

#pragma unroll
  for (int jt = 0; jt < 4; jt++) {
    const int n = n0 + wn + jt * 16 + col;
    const float bn = (omode == 2 && kc != 0) ? 0.f : bias[n];
    if (omode == 1) {
#pragma unroll
      for (int i = 0; i < 4; i++) {
        const int mg = m0 + wm + i * 16 + quad * 4;
        const int bb = mg >> 11, tl = mg & 2047;
        ushort4 o;
        o.x = f2bf(acc[i][jt][0] + bn);
        o.y = f2bf(acc[i][jt][1] + bn);
        o.z = f2bf(acc[i][jt][2] + bn);
        o.w = f2bf(acc[i][jt][3] + bn);
        *(ushort4*)((u16*)Yv + (size_t)bb * Dd * Tt + (size_t)n * Tt + tl) = o;
      }
    } else if (omode == 0) {
      u16* Y = (u16*)Yv;
#pragma unroll
      for (int i = 0; i < 4; i++)
#pragma unroll
        for (int r = 0; r < 4; r++) {
          const int m = m0 + wm + i * 16 + quad * 4 + r;
          Y[(size_t)m * Dd + n] = f2bf((acc[i][jt][r] + bn) * oscale);
        }
    } else {
      float* Y = (float*)Yv;
#pragma unroll
      for (int i = 0; i < 4; i++)
#pragma unroll
        for (int r = 0; r < 4; r++) {
          const int m = m0 + wm + i * 16 + quad * 4 + r;
          atomicAdd(&Y[(size_t)m * Dd + n], acc[i][jt][r] + bn);
        }
    }
  }
}

// Fused Q/K/V projection; Q scaled by log2(e)/8 so attention uses exp2.
__global__ __launch_bounds__(256) void proj_qkv(
    const u16* __restrict__ Xb, const u16* __restrict__ Wb,
    const float* __restrict__ bq, const float* __restrict__ bk,
    const float* __restrict__ bv,
    u16* __restrict__ Qp, u16* __restrict__ Kp, u16* __restrict__ VtG)
{
  __shared__ u16 As[128 * 64];
  __shared__ u16 Bs[128 * 64];
  const int z = blockIdx.z;
  const u16* X = Xb + (size_t)z * Mm * Dd;
  const u16* W = Wb + (size_t)z * Dd * Dd;
  const float* bias = z == 0 ? bq : z == 1 ? bk : bv;
  void* Y = z == 0 ? (void*)Qp : z == 1 ? (void*)Kp : (void*)VtG;
  const float qs = 0.125f * 1.44269504088896f;  // 1/sqrt(nd) * log2(e)
  gemm_body(X, W, bias, Y, z == 0 ? qs : 1.0f, z == 2 ? 1 : 0, 0, 1, As, Bs);
}

__global__ __launch_bounds__(256) void gemm_final(
    const u16* __restrict__ Ctx, const u16* __restrict__ Wcb,
    const float* __restrict__ bc, float* __restrict__ out)
{
  __shared__ u16 As[128 * 64];
  __shared__ u16 Bs[128 * 64];
  gemm_body(Ctx, Wcb, bc, out, 1.0f, 2, blockIdx.z, 2, As, Bs);
}

// ctx f32 accumulator -> bf16 for gemm_final's DMA path
__global__ __launch_bounds__(256) void cvt_ctx(
    const float* __restrict__ Ctx32, u16* __restrict__ Ctxb)
{
  const int vid = blockIdx.x * 256 + threadIdx.x;  // 1M vec4 units
  float4 f = *(const float4*)(Ctx32 + (size_t)vid * 4);
  ushort4 o;
  o.x = f2bf(f.x); o.y = f2bf(f.y); o.z = f2bf(f.z); o.w = f2bf(f.w);
  *(ushort4*)(Ctxb + (size_t)vid * 4) = o;
}

// ---------------------------------------------------------------------------
// Pass A: lsum[tk] += partial sum_{tq>=tk} exp2(z).  Block: (bh, 128 tk,
// chunk c). Wave: 32 tk (A-strips in regs). Also zeroes the ctx accumulator
// (runs after proj_qkv, before attn_out — stream-ordered).
// ---------------------------------------------------------------------------
__global__ __launch_bounds__(256) void attn_stats(
    const u16* __restrict__ Qp, const u16* __restrict__ Kp,
    float* __restrict__ lsum, float* __restrict__ Ctx32z)
{
  __shared__ u16 Ks[128 * 64];
  __shared__ u16 Qs[128 * 64];
  const int t = threadIdx.x, lane = t & 63, w = t >> 6;
  const int col = lane & 15, quad = lane >> 4;
  const int bh = blockIdx.x, b = bh >> 4, h = bh & 15;
  const int j = blockIdx.y, tk0 = j * 128, c = blockIdx.z;
  const u16* Kbase = Kp + (size_t)b * Tt * Dd + h * NDh;
  const u16* Qbase = Qp + (size_t)b * Tt * Dd + h * NDh;
  const int drr = lane >> 3, dsw = ((lane & 7) ^ drr) * 8;

  {  // zero ctx accumulator: 1024 blocks x 256 thr x 4 float4 = 16 MB
    const size_t zid = ((size_t)(blockIdx.z * gridDim.y + blockIdx.y) * gridDim.x
                        + blockIdx.x) * 256 + t;
#pragma unroll
    for (int i = 0; i < 4; i++)
      *(float4*)(Ctx32z + (zid + (size_t)i * 262144) * 4) =
          make_float4(0.f, 0.f, 0.f, 0.f);
  }

#pragma unroll
  for (int i = 0; i < 4; i++) {
    const int rr = w * 32 + i * 8;
    ldsdma16(Kbase + (size_t)(tk0 + rr + drr) * Dd + dsw, Ks + rr * 64);
  }
  __syncthreads();
  bf16x8 ka[2][2];
#pragma unroll
  for (int s2 = 0; s2 < 2; s2++) {
    const int row = w * 32 + s2 * 16 + col;
    ka[s2][0] = ldfrag(Ks, row, quad);
    ka[s2][1] = ldfrag(Ks, row, 4 + quad);
  }

  float l[2][4] = {};

  for (int jj = j + c; jj < Tt / 128; jj += 2) {
    const bool masked = (jj == j);
    const int tq0 = jj * 128;
    __syncthreads();  // prev Qs readers done
#pragma unroll
    for (int i = 0; i < 4; i++) {
      const int rr = w * 32 + i * 8;
      ldsdma16(Qbase + (size_t)(tq0 + rr + drr) * Dd + dsw, Qs + rr * 64);
    }
    __syncthreads();
#pragma unroll
    for (int jt = 0; jt < 8; jt++) {
      bf16x8 qb0 = ldfrag(Qs, jt * 16 + col, quad);
      bf16x8 qb1 = ldfrag(Qs, jt * 16 + col, 4 + quad);
      const int tq = tq0 + jt * 16 + col;
#pragma unroll
      for (int s2 = 0; s2 < 2; s2++) {
        f32x4 z = {};
        z = MFMA(ka[s2][0], qb0, z);
        z = MFMA(ka[s2][1], qb1, z);
#pragma unroll
        for (int r = 0; r < 4; r++) {
          float e = fexp2(z[r]);
          if (masked) {
            const int tk = tk0 + w * 32 + s2 * 16 + quad * 4 + r;
            e = (tq >= tk) ? e : 0.f;
          }
          l[s2][r] += e;
        }
      }
    }
  }

#pragma unroll
  for (int s2 = 0; s2 < 2; s2++)
#pragma unroll
    for (int r = 0; r < 4; r++) {
      float s = l[s2][r];
#pragma unroll
      for (int m = 1; m < 16; m <<= 1) s += __shfl_xor(s, m);
      if (col == 0)
        atomicAdd(&lsum[(size_t)bh * Tt + tk0 + w * 32 + s2 * 16 + quad * 4 + r], s);
    }
}

// ---------------------------------------------------------------------------
// Pass B: out[tq] = sum_{tk<=tq} exp2(z)/l[tk] * v[tk].
// Grid (bh, 16 tq-tiles of 128, 2 tk-chunks); chunk c does tk-tiles it≡c mod 2
// (halves the serial chain — round-8 critical path). Partial O atomicAdd'd
// into f32 Ctx32. V pre-transposed VtG[b,h*64+d,t]. Q LDS reused as P.
// ---------------------------------------------------------------------------
__global__ __launch_bounds__(256) void attn_out(
    const u16* __restrict__ Qp, const u16* __restrict__ Kp,
    const u16* __restrict__ VtG, const float* __restrict__ lsum,
    float* __restrict__ Ctx32)
{
  __shared__ u16 QPs[128 * 64];  // Q at start, then P (wave-private rows)
  __shared__ u16 Ks[64 * 64];
  __shared__ u16 Vts[64 * 64];   // [d][tk]
  __shared__ float srl[64];
  const int t = threadIdx.x, lane = t & 63, w = t >> 6;
  const int col = lane & 15, quad = lane >> 4;
  const int bh = blockIdx.x, b = bh >> 4, h = bh & 15;
  const int tq0 = (gridDim.y - 1 - blockIdx.y) * 128;   // heavy-first
  const int c = blockIdx.z;
  const u16* Qbase = Qp + (size_t)b * Tt * Dd + h * NDh;
  const u16* Kbase = Kp + (size_t)b * Tt * Dd + h * NDh;
  const u16* Vbase = VtG + (size_t)b * Dd * Tt + (size_t)h * NDh * Tt;
  const int drr = lane >> 3, dsw = ((lane & 7) ^ drr) * 8;

#pragma unroll
  for (int i = 0; i < 4; i++) {
    const int rr = w * 32 + i * 8;
    ldsdma16(Qbase + (size_t)(tq0 + rr + drr) * Dd + dsw, QPs + rr * 64);
  }
  __syncthreads();
  bf16x8 qa[2][2];
#pragma unroll
  for (int s2 = 0; s2 < 2; s2++) {
    const int row = w * 32 + s2 * 16 + col;
    qa[s2][0] = ldfrag(QPs, row, quad);
    qa[s2][1] = ldfrag(QPs, row, 4 + quad);
  }

  f32x4 o[2][4] = {};

  for (int it = c; it * 64 < tq0 + 128; it += 2) {
    const int tk0 = it * 64;
    const bool masked = (tk0 >= tq0);
    __syncthreads();  // prev iter LDS readers done
#pragma unroll
    for (int i = 0; i < 2; i++) {
      const int rr = w * 16 + i * 8;
      ldsdma16(Kbase + (size_t)(tk0 + rr + drr) * Dd + dsw, Ks + rr * 64);
      ldsdma16(Vbase + (size_t)(rr + drr) * Tt + tk0 + dsw, Vts + rr * 64);
    }
    if (t < 64) srl[t] = 1.0f / lsum[(size_t)bh * Tt + tk0 + t];
    __syncthreads();
#pragma unroll
    for (int jt = 0; jt < 4; jt++) {
      bf16x8 kb0 = ldfrag(Ks, jt * 16 + col, quad);
      bf16x8 kb1 = ldfrag(Ks, jt * 16 + col, 4 + quad);
      const int tkl = jt * 16 + col;
      const float rl = srl[tkl];
#pragma unroll
      for (int s2 = 0; s2 < 2; s2++) {
        f32x4 z = {};
        z = MFMA(qa[s2][0], kb0, z);
        z = MFMA(qa[s2][1], kb1, z);
#pragma unroll
        for (int r = 0; r < 4; r++) {
          const int row = w * 32 + s2 * 16 + quad * 4 + r;
          float p = fexp2(z[r]) * rl;
          if (masked) p = (tk0 + tkl <= tq0 + row) ? p : 0.f;
          QPs[row * 64 + (((tkl >> 3) ^ (row & 7)) * 8) + (tkl & 7)] = f2bf(p);
        }
      }
    }
    // no barrier: each wave reads only its own 32 P rows (same-wave LDS order)
    bf16x8 pa[2][2];
#pragma unroll
    for (int s2 = 0; s2 < 2; s2++) {
      const int row = w * 32 + s2 * 16 + col;
      pa[s2][0] = ldfrag(QPs, row, quad);
      pa[s2][1] = ldfrag(QPs, row, 4 + quad);
    }
#pragma unroll
    for (int dn = 0; dn < 4; dn++) {
      bf16x8 vb0 = ldfrag(Vts, dn * 16 + col, quad);
      bf16x8 vb1 = ldfrag(Vts, dn * 16 + col, 4 + quad);
#pragma unroll
      for (int s2 = 0; s2 < 2; s2++) {
        o[s2][dn] = MFMA(pa[s2][0], vb0, o[s2][dn]);
        o[s2][dn] = MFMA(pa[s2][1], vb1, o[s2][dn]);
      }
    }
  }

#pragma unroll
  for (int s2 = 0; s2 < 2; s2++)
#pragma unroll
    for (int dn = 0; dn < 4; dn++)
#pragma unroll
      for (int r = 0; r < 4; r++) {
        const int tq = tq0 + w * 32 + s2 * 16 + quad * 4 + r;
        atomicAdd(&Ctx32[(size_t)(b * Tt + tq) * Dd + h * NDh + dn * 16 + col],
                  o[s2][dn][r]);
      }
}

// ---------------------------------------------------------------------------
extern "C" void kernel_launch(void* const* d_in, const int* in_sizes, int n_in,
                              void* d_out, int out_size, void* d_ws, size_t ws_size,
                              hipStream_t stream)
{
  const float* q  = (const float*)d_in[0];
  const float* k  = (const float*)d_in[1];
  const float* v  = (const float*)d_in[2];
  const float* Wq = (const float*)d_in[3];
  const float* bq = (const float*)d_in[4];
  const float* Wk = (const float*)d_in[5];
  const float* bk = (const float*)d_in[6];
  const float* Wv = (const float*)d_in[7];
  const float* bv = (const float*)d_in[8];
  const float* Wc = (const float*)d_in[9];
  const float* bc = (const float*)d_in[10];

  u16* Wb   = (u16*)d_ws;                         // 4 * Dd*Dd
  u16* Xb   = Wb + (size_t)4 * Dd * Dd;           // 3 * Mm*Dd (q,k,v bf16)
  float* Ctx32 = (float*)Xb;                      // aliases Xb (dead after proj)
  u16* Qp   = Xb + (size_t)3 * Mm * Dd;
  u16* Kp   = Qp + (size_t)Mm * Dd;
  u16* VtG  = Kp + (size_t)Mm * Dd;               // [B, D, T] transposed
  u16* Ctxb = VtG + (size_t)Mm * Dd;
  float* lsum = (float*)(Ctxb + (size_t)Mm * Dd); // Bb*Hh*Tt

  cvt_all<<<16384, 256, 0, stream>>>(Wq, Wk, Wv, Wc, q, k, v, Wb, Xb,
                                     (float*)d_out, lsum);
  proj_qkv<<<dim3(Mm / 128, Dd / 128, 3), 256, 0, stream>>>(
      Xb, Wb, bq, bk, bv, Qp, Kp, VtG);
  attn_stats<<<dim3(Bb * Hh, Tt / 128, 2), 256, 0, stream>>>(Qp, Kp, lsum, Ctx32);
  attn_out<<<dim3(Bb * Hh, Tt / 128, 2), 256, 0, stream>>>(Qp, Kp, VtG, lsum, Ctx32);
  cvt_ctx<<<4096, 256, 0, stream>>>(Ctx32, Ctxb);
  gemm_final<<<dim3(Mm / 128, Dd / 128, 2), 256, 0, stream>>>(
      Ctxb, Wb + (size_t)3 * Dd * Dd, bc, (float*)d_out);
}